// Round 14
// baseline (166.659 us; speedup 1.0000x reference)
//
#include <hip/hip_runtime.h>
#include <hip/hip_bf16.h>

#define N_ROWS 16384
#define M_ROWS 16384
#define DIM 256
#define JT 32           // y-cols per j-iter
#define NJ 64           // j-iters per block (JT*NJ = 2048-col chunk)

typedef __attribute__((ext_vector_type(4))) float f32x4;
typedef __attribute__((ext_vector_type(8))) short bf16x8;

__device__ inline unsigned enc_f(float f) {
  unsigned u = __float_as_uint(f);
  return (u & 0x80000000u) ? ~u : (u | 0x80000000u);
}
__device__ inline float dec_f(unsigned u) {
  unsigned b = (u & 0x80000000u) ? (u & 0x7FFFFFFFu) : ~u;
  return __uint_as_float(b);
}
__device__ inline unsigned short f2bf(float f) {
  unsigned u = __float_as_uint(f);
  u += 0x7FFFu + ((u >> 16) & 1u);
  return (unsigned short)(u >> 16);
}

// Fused prep: blocks [0,4096) convert x -> xb (row-major) + x2 + rowmin init;
// blocks [4096,8192) convert y -> yb2 (fragment-major tiles) + (y2 - psi).
// yb2: tile t = (row>>4)*8 + (k>>5); within tile (512 shorts):
// off = (row&15)*32 + (k&31). One tile = one 16-col x 32-k B-fragment set ->
// the gemm reads it as ONE fully-coalesced 1-KB global_load per wave.
__global__ __launch_bounds__(256) void prep_kernel(
    const float* __restrict__ x, const float* __restrict__ y,
    const float* __restrict__ psi,
    unsigned short* __restrict__ xb, unsigned short* __restrict__ yb2,
    float* __restrict__ x2, float* __restrict__ rj,
    unsigned int* __restrict__ rowmin) {
  int bid  = blockIdx.x;
  int isY  = bid >= (N_ROWS / 4);
  int rb   = isY ? bid - N_ROWS / 4 : bid;
  int row  = rb * 4 + (threadIdx.x >> 6);
  int lane = threadIdx.x & 63;
  const float* in = isY ? y : x;
  const float4 v = *reinterpret_cast<const float4*>(in + (size_t)row * DIM + lane * 4);
  ushort4 b;
  b.x = f2bf(v.x); b.y = f2bf(v.y); b.z = f2bf(v.z); b.w = f2bf(v.w);
  if (isY) {
    int k0   = lane * 4;
    int tile = (row >> 4) * 8 + (k0 >> 5);
    int off  = (row & 15) * 32 + (k0 & 31);
    *reinterpret_cast<ushort4*>(yb2 + (size_t)tile * 512 + off) = b;
  } else {
    *reinterpret_cast<ushort4*>(xb + (size_t)row * DIM + lane * 4) = b;
  }
  float s = v.x * v.x + v.y * v.y + v.z * v.z + v.w * v.w;
#pragma unroll
  for (int m = 1; m < 64; m <<= 1) s += __shfl_xor(s, m, 64);
  if (lane == 0) {
    if (isY) rj[row] = s - psi[row];
    else { x2[row] = s; rowmin[row] = 0xFFFFFFFFu; }
  }
}

// Register-resident-A (64 rows/wave, AGPR-pinned), M-streaming GEMM+min.
// NO LDS, NO barriers: B fragments stream global(L1/L2)->register through a
// 4-slot ring with prefetch distance 3, CONTINUOUS across j-iters
// (slot = ks&3 is j-invariant). Waves free-run; SGB interleaves
// {1 VMEM, 4 MFMA} x2 per ks so loads ride under the MFMA clusters.
__global__ __launch_bounds__(256, 2) void gemm_min_kernel(
    const unsigned short* __restrict__ xb, const unsigned short* __restrict__ yb2,
    const float* __restrict__ rj, unsigned int* __restrict__ rowmin) {
  const int bid    = blockIdx.x;       // 512 blocks, 2 per CU
  const int jchunk = bid & 7;          // == XCD id under round-robin dispatch
  const int strip  = bid >> 3;         // 0..63
  const int brow   = strip * 256;
  const int jbase0 = jchunk * (JT * NJ);

  const int tid = threadIdx.x;
  const int w = tid >> 6, lane = tid & 63;
  const int fr = lane & 15, g4 = lane >> 4;

  // ---- A fragments: rows brow + w*64 + m*16 + fr, k = ks*32 + g4*8; AGPR-pinned.
  bf16x8 afr[4][8];
  {
    const unsigned short* aBase = xb + (size_t)(brow + w * 64 + fr) * DIM + g4 * 8;
#pragma unroll
    for (int m = 0; m < 4; ++m)
#pragma unroll
      for (int ks = 0; ks < 8; ++ks) {
        afr[m][ks] = *reinterpret_cast<const bf16x8*>(aBase + (size_t)(m * 16) * DIM + ks * 32);
        asm volatile("" : "+a"(afr[m][ks]));  // pin in AGPR file
      }
  }
  __builtin_amdgcn_sched_barrier(0);

  // ---- B fragment pointers: chunk base + per-lane slot inside each 1-KB tile.
  // cluster (j, n, ks) -> tile (jchunk*128 + j*2 + n)*8 + ks.
  const unsigned short* bbase = yb2 + (size_t)jchunk * 1024 * 512 + fr * 32 + g4 * 8;
#define BPTR(j, n, ks) \
  (bbase + (size_t)(((j) * 2 + (n)) * 8 + (ks)) * 512)

  const float* rjc = rj + jbase0;
  float mn[4][4];
#pragma unroll
  for (int m = 0; m < 4; ++m)
#pragma unroll
    for (int r = 0; r < 4; ++r) mn[m][r] = 3.4e38f;

  // Prologue: fill ring slots 0..2 with clusters 0..2 of j=0.
  bf16x8 pb0[4], pb1[4];
  pb0[0] = *reinterpret_cast<const bf16x8*>(BPTR(0, 0, 0));
  pb1[0] = *reinterpret_cast<const bf16x8*>(BPTR(0, 1, 0));
  pb0[1] = *reinterpret_cast<const bf16x8*>(BPTR(0, 0, 1));
  pb1[1] = *reinterpret_cast<const bf16x8*>(BPTR(0, 1, 1));
  pb0[2] = *reinterpret_cast<const bf16x8*>(BPTR(0, 0, 2));
  pb1[2] = *reinterpret_cast<const bf16x8*>(BPTR(0, 1, 2));

#pragma unroll 1
  for (int j = 0; j < NJ; ++j) {
    float rv0 = rjc[j * JT + fr];
    float rv1 = rjc[j * JT + 16 + fr];
    const int jn = (j + 1 < NJ) ? j + 1 : j;  // clamp (redundant loads, unused)

    f32x4 acc[4][2];
#pragma unroll
    for (int m = 0; m < 4; ++m)
#pragma unroll
      for (int n = 0; n < 2; ++n) acc[m][n] = (f32x4){0.f, 0.f, 0.f, 0.f};

    __builtin_amdgcn_s_setprio(1);
    __builtin_amdgcn_sched_barrier(0);
#pragma unroll
    for (int ks = 0; ks < 8; ++ks) {
      // prefetch cluster ks+3 (wrapping into next j) into slot (ks+3)&3
      const int ps = (ks + 3) & 3;
      if (ks < 5) {
        pb0[ps] = *reinterpret_cast<const bf16x8*>(BPTR(j, 0, ks + 3));
        pb1[ps] = *reinterpret_cast<const bf16x8*>(BPTR(j, 1, ks + 3));
      } else {
        pb0[ps] = *reinterpret_cast<const bf16x8*>(BPTR(jn, 0, ks - 5));
        pb1[ps] = *reinterpret_cast<const bf16x8*>(BPTR(jn, 1, ks - 5));
      }
      const int cs = ks & 3;
#pragma unroll
      for (int m = 0; m < 4; ++m) {
        acc[m][0] = __builtin_amdgcn_mfma_f32_16x16x32_bf16(afr[m][ks], pb0[cs], acc[m][0], 0, 0, 0);
        acc[m][1] = __builtin_amdgcn_mfma_f32_16x16x32_bf16(afr[m][ks], pb1[cs], acc[m][1], 0, 0, 0);
      }
      // Pin emission: 1 vmem + 4 mfma, twice per ks.
      __builtin_amdgcn_sched_group_barrier(0x020, 1, 0);  // VMEM_READ
      __builtin_amdgcn_sched_group_barrier(0x008, 4, 0);  // MFMA
      __builtin_amdgcn_sched_group_barrier(0x020, 1, 0);
      __builtin_amdgcn_sched_group_barrier(0x008, 4, 0);
    }
    __builtin_amdgcn_sched_barrier(0);
    __builtin_amdgcn_s_setprio(0);

    // fold: val = rv - 2*dot ; running min
#pragma unroll
    for (int m = 0; m < 4; ++m)
#pragma unroll
      for (int r = 0; r < 4; ++r) {
        mn[m][r] = fminf(mn[m][r], fmaf(-2.f, acc[m][0][r], rv0));
        mn[m][r] = fminf(mn[m][r], fmaf(-2.f, acc[m][1][r], rv1));
      }
  }
#undef BPTR

  // Row-min over chunk: reduce min over the 16 fr-lanes, then one atomic per row.
#pragma unroll
  for (int m = 0; m < 4; ++m)
#pragma unroll
    for (int r = 0; r < 4; ++r) {
      float v = mn[m][r];
#pragma unroll
      for (int s = 1; s < 16; s <<= 1) v = fminf(v, __shfl_xor(v, s, 64));
      if (fr == 0) {
        int row = brow + w * 64 + m * 16 + g4 * 4 + r;
        atomicMin(&rowmin[row], enc_f(v));
      }
    }
}

__global__ __launch_bounds__(256) void finish_kernel(
    const float* __restrict__ x2, const unsigned int* __restrict__ rowmin,
    const float* __restrict__ psi, float* __restrict__ out) {
  int tid = threadIdx.x;
  double s0 = 0.0, s1 = 0.0;
  for (int i = tid; i < N_ROWS; i += 256) {
    s0 += (double)x2[i] + (double)dec_f(rowmin[i]);
    s1 += (double)psi[i];
  }
  __shared__ double sm0[4], sm1[4];
#pragma unroll
  for (int m = 1; m < 64; m <<= 1) { s0 += __shfl_xor(s0, m, 64); s1 += __shfl_xor(s1, m, 64); }
  if ((tid & 63) == 0) { sm0[tid >> 6] = s0; sm1[tid >> 6] = s1; }
  __syncthreads();
  if (tid == 0) {
    out[0] = (float)((sm0[0] + sm0[1] + sm0[2] + sm0[3]) / (double)N_ROWS);
    out[1] = (float)((sm1[0] + sm1[1] + sm1[2] + sm1[3]) / (double)M_ROWS);
  }
}

extern "C" void kernel_launch(void* const* d_in, const int* in_sizes, int n_in,
                              void* d_out, int out_size, void* d_ws, size_t ws_size,
                              hipStream_t stream) {
  const float* x   = (const float*)d_in[0];
  const float* y   = (const float*)d_in[1];
  const float* psi = (const float*)d_in[2];
  float* out = (float*)d_out;

  char* ws = (char*)d_ws;
  unsigned short* xb  = (unsigned short*)ws;                                 // 8 MB
  unsigned short* yb2 = (unsigned short*)(ws + (size_t)N_ROWS * DIM * 2);    // 8 MB (tiled)
  float* x2 = (float*)(ws + (size_t)(N_ROWS + M_ROWS) * DIM * 2);            // 64 KB
  float* rj = x2 + N_ROWS;                                                   // 64 KB (y2 - psi)
  unsigned int* rowmin = (unsigned int*)(rj + M_ROWS);                       // 64 KB

  prep_kernel<<<(N_ROWS + M_ROWS) / 4, 256, 0, stream>>>(x, y, psi, xb, yb2, x2, rj, rowmin);
  gemm_min_kernel<<<(N_ROWS / 256) * 8, 256, 0, stream>>>(xb, yb2, rj, rowmin);
  finish_kernel<<<1, 256, 0, stream>>>(x2, rowmin, psi, out);
}

// Round 15
// 125.208 us; speedup vs baseline: 1.3311x; 1.3311x over previous
//
#include <hip/hip_runtime.h>
#include <hip/hip_bf16.h>

#define N_ROWS 16384
#define M_ROWS 16384
#define DIM 256
#define JT 32           // y-cols per j-iter
#define NJ 64           // j-iters per block (JT*NJ = 2048-col chunk)

typedef __attribute__((ext_vector_type(4))) float f32x4;
typedef __attribute__((ext_vector_type(8))) short bf16x8;

__device__ inline unsigned enc_f(float f) {
  unsigned u = __float_as_uint(f);
  return (u & 0x80000000u) ? ~u : (u | 0x80000000u);
}
__device__ inline float dec_f(unsigned u) {
  unsigned b = (u & 0x80000000u) ? (u & 0x7FFFFFFFu) : ~u;
  return __uint_as_float(b);
}
__device__ inline unsigned short f2bf(float f) {
  unsigned u = __float_as_uint(f);
  u += 0x7FFFu + ((u >> 16) & 1u);
  return (unsigned short)(u >> 16);
}

// Fused prep: blocks [0,4096) convert x -> xb + x2 + rowmin init;
// blocks [4096,8192) convert y -> yb + (y2 - psi).
__global__ __launch_bounds__(256) void prep_kernel(
    const float* __restrict__ x, const float* __restrict__ y,
    const float* __restrict__ psi,
    unsigned short* __restrict__ xb, unsigned short* __restrict__ yb,
    float* __restrict__ x2, float* __restrict__ rj,
    unsigned int* __restrict__ rowmin) {
  int bid  = blockIdx.x;
  int isY  = bid >= (N_ROWS / 4);
  int rb   = isY ? bid - N_ROWS / 4 : bid;
  int row  = rb * 4 + (threadIdx.x >> 6);
  int lane = threadIdx.x & 63;
  const float* in = isY ? y : x;
  unsigned short* outb = isY ? yb : xb;
  const float4 v = *reinterpret_cast<const float4*>(in + (size_t)row * DIM + lane * 4);
  ushort4 b;
  b.x = f2bf(v.x); b.y = f2bf(v.y); b.z = f2bf(v.z); b.w = f2bf(v.w);
  *reinterpret_cast<ushort4*>(outb + (size_t)row * DIM + lane * 4) = b;
  float s = v.x * v.x + v.y * v.y + v.z * v.z + v.w * v.w;
#pragma unroll
  for (int m = 1; m < 64; m <<= 1) s += __shfl_xor(s, m, 64);
  if (lane == 0) {
    if (isY) rj[row] = s - psi[row];
    else { x2[row] = s; rowmin[row] = 0xFFFFFFFFu; }
  }
}

// R12 gemm (best measured: 109.2 us): register-resident-A (AGPR-pinned),
// M-streaming, fragment-major LDS, 3-deep ring, counted vmcnt(4),
// 2-deep B-fragment ring + sched_group_barrier {2 DS_READ, 8 MFMA}.
__global__ __launch_bounds__(256, 2) void gemm_min_kernel(
    const unsigned short* __restrict__ xb, const unsigned short* __restrict__ yb,
    const float* __restrict__ rj, unsigned int* __restrict__ rowmin) {
  __shared__ unsigned short Bt[3][JT * DIM];  // 3 x 16 KiB

  const int bid    = blockIdx.x;       // 512 blocks, 2 per CU
  const int jchunk = bid & 7;          // == XCD id under round-robin dispatch
  const int strip  = bid >> 3;         // 0..63
  const int brow   = strip * 256;
  const int jbase0 = jchunk * (JT * NJ);

  const int tid = threadIdx.x;
  const int w = tid >> 6, lane = tid & 63;
  const int fr = lane & 15, g4 = lane >> 4;

  // ---- A fragments: rows brow + w*64 + m*16 + fr, k = ks*32 + g4*8; AGPR-pinned.
  bf16x8 afr[4][8];
  {
    const unsigned short* aBase = xb + (size_t)(brow + w * 64 + fr) * DIM + g4 * 8;
#pragma unroll
    for (int m = 0; m < 4; ++m)
#pragma unroll
      for (int ks = 0; ks < 8; ++ks) {
        afr[m][ks] = *reinterpret_cast<const bf16x8*>(aBase + (size_t)(m * 16) * DIM + ks * 32);
        asm volatile("" : "+a"(afr[m][ks]));  // pin in AGPR file
      }
  }
  __builtin_amdgcn_sched_barrier(0);

  // ---- staging: wave w stages chunks cc = w*4..w*4+3 (1KB each).
  // chunk cc = n*8 + ks; LDS[cc*1024 + lane*16] = yb[row: j*JT + n*16 + (lane>>2),
  // k: ks*32 + (lane&3)*8] -- lane-linear dest, permuted global source.
  const int srow = lane >> 2;          // 0..15 row within col-group
  const int scol = (lane & 3) * 8;     // k elems within 32-k slice

#define STAGE(buf, j)                                                            \
  {                                                                              \
    _Pragma("unroll")                                                            \
    for (int c = 0; c < 4; ++c) {                                                \
      const int cc = w * 4 + c;                                                  \
      const int sn = cc >> 3, sk = cc & 7;                                       \
      __builtin_amdgcn_global_load_lds(                                          \
          (const __attribute__((address_space(1))) void*)(                       \
              yb + (size_t)(jbase0 + (j) * JT + sn * 16 + srow) * DIM + sk * 32 + scol), \
          (__attribute__((address_space(3))) void*)(&Bt[(buf)][cc * 512]), 16, 0, 0); \
    }                                                                            \
  }

  STAGE(0, 0);
  STAGE(1, 1);

  const float* rjc = rj + jbase0;
  float mn[4][4];
#pragma unroll
  for (int m = 0; m < 4; ++m)
#pragma unroll
    for (int r = 0; r < 4; ++r) mn[m][r] = 3.4e38f;

  int rb = 0;  // ring read index
#pragma unroll 1
  for (int j = 0; j < NJ; ++j) {
    if (j == NJ - 1) { asm volatile("s_waitcnt vmcnt(0)" ::: "memory"); }
    else             { asm volatile("s_waitcnt vmcnt(4)" ::: "memory"); }
    __builtin_amdgcn_sched_barrier(0);
    __builtin_amdgcn_s_barrier();
    __builtin_amdgcn_sched_barrier(0);

    // rv loads issued early; consumed only at iter end (latency hidden by MFMA).
    float rv0 = rjc[j * JT + fr];
    float rv1 = rjc[j * JT + 16 + fr];
    __builtin_amdgcn_sched_barrier(0);
    if (j + 2 < NJ) {
      int sb = rb + 2; if (sb >= 3) sb -= 3;
      STAGE(sb, j + 2);
    }
    __builtin_amdgcn_sched_barrier(0);

    f32x4 acc[4][2];
#pragma unroll
    for (int m = 0; m < 4; ++m)
#pragma unroll
      for (int n = 0; n < 2; ++n) acc[m][n] = (f32x4){0.f, 0.f, 0.f, 0.f};

    const unsigned short* B = &Bt[rb][0];
    // Fragment address: chunk (n*8+ks)*512 shorts + fr*32 + g4*8 shorts.
#define BADDR(n, ks) (((n) * 8 + (ks)) * 512 + fr * 32 + g4 * 8)
    // 2-deep B-fragment prefetch ring (indices compile-time after full unroll).
    bf16x8 pb0[3], pb1[3];
    pb0[0] = *reinterpret_cast<const bf16x8*>(&B[BADDR(0, 0)]);
    pb1[0] = *reinterpret_cast<const bf16x8*>(&B[BADDR(1, 0)]);
    pb0[1] = *reinterpret_cast<const bf16x8*>(&B[BADDR(0, 1)]);
    pb1[1] = *reinterpret_cast<const bf16x8*>(&B[BADDR(1, 1)]);

    __builtin_amdgcn_s_setprio(1);
    __builtin_amdgcn_sched_barrier(0);
#pragma unroll
    for (int ks = 0; ks < 8; ++ks) {
      const int cs = ks % 3;
      const int ns = (ks + 2) % 3;
      if (ks < 6) {
        pb0[ns] = *reinterpret_cast<const bf16x8*>(&B[BADDR(0, ks + 2)]);
        pb1[ns] = *reinterpret_cast<const bf16x8*>(&B[BADDR(1, ks + 2)]);
      }
#pragma unroll
      for (int m = 0; m < 4; ++m) {
        acc[m][0] = __builtin_amdgcn_mfma_f32_16x16x32_bf16(afr[m][ks], pb0[cs], acc[m][0], 0, 0, 0);
        acc[m][1] = __builtin_amdgcn_mfma_f32_16x16x32_bf16(afr[m][ks], pb1[cs], acc[m][1], 0, 0, 0);
      }
      // Pin emission: 2 ds_reads ride under each 8-MFMA cluster.
      if (ks < 6) {
        __builtin_amdgcn_sched_group_barrier(0x100, 2, 0);  // 2 DS_READ
        __builtin_amdgcn_sched_group_barrier(0x008, 8, 0);  // 8 MFMA
      } else {
        __builtin_amdgcn_sched_group_barrier(0x008, 8, 0);  // 8 MFMA
      }
    }
    __builtin_amdgcn_sched_barrier(0);
#undef BADDR
    __builtin_amdgcn_s_setprio(0);

    // fold: val = rv - 2*dot ; running min
#pragma unroll
    for (int m = 0; m < 4; ++m)
#pragma unroll
      for (int r = 0; r < 4; ++r) {
        mn[m][r] = fminf(mn[m][r], fmaf(-2.f, acc[m][0][r], rv0));
        mn[m][r] = fminf(mn[m][r], fmaf(-2.f, acc[m][1][r], rv1));
      }
    rb = rb + 1; if (rb >= 3) rb -= 3;
  }
#undef STAGE

  // Row-min over chunk: reduce min over the 16 fr-lanes, then one atomic per row.
#pragma unroll
  for (int m = 0; m < 4; ++m)
#pragma unroll
    for (int r = 0; r < 4; ++r) {
      float v = mn[m][r];
#pragma unroll
      for (int s = 1; s < 16; s <<= 1) v = fminf(v, __shfl_xor(v, s, 64));
      if (fr == 0) {
        int row = brow + w * 64 + m * 16 + g4 * 4 + r;
        atomicMin(&rowmin[row], enc_f(v));
      }
    }
}

// Stage 1: 64 blocks; block b sums rows [b*256, (b+1)*256) of x2+rowmin (and
// psi) into partials — fixed reduction order, deterministic.
__global__ __launch_bounds__(256) void finish1_kernel(
    const float* __restrict__ x2, const unsigned int* __restrict__ rowmin,
    const float* __restrict__ psi, double* __restrict__ partials) {
  int tid = threadIdx.x;
  int i = blockIdx.x * 256 + tid;
  double s0 = (double)x2[i] + (double)dec_f(rowmin[i]);
  double s1 = (double)psi[i];
  __shared__ double sm0[4], sm1[4];
#pragma unroll
  for (int m = 1; m < 64; m <<= 1) { s0 += __shfl_xor(s0, m, 64); s1 += __shfl_xor(s1, m, 64); }
  if ((tid & 63) == 0) { sm0[tid >> 6] = s0; sm1[tid >> 6] = s1; }
  __syncthreads();
  if (tid == 0) {
    partials[blockIdx.x]      = sm0[0] + sm0[1] + sm0[2] + sm0[3];
    partials[64 + blockIdx.x] = sm1[0] + sm1[1] + sm1[2] + sm1[3];
  }
}

// Stage 2: one wave reduces the 64 partials.
__global__ __launch_bounds__(64) void finish2_kernel(
    const double* __restrict__ partials, float* __restrict__ out) {
  int lane = threadIdx.x;
  double s0 = partials[lane];
  double s1 = partials[64 + lane];
#pragma unroll
  for (int m = 1; m < 64; m <<= 1) { s0 += __shfl_xor(s0, m, 64); s1 += __shfl_xor(s1, m, 64); }
  if (lane == 0) {
    out[0] = (float)(s0 / (double)N_ROWS);
    out[1] = (float)(s1 / (double)M_ROWS);
  }
}

extern "C" void kernel_launch(void* const* d_in, const int* in_sizes, int n_in,
                              void* d_out, int out_size, void* d_ws, size_t ws_size,
                              hipStream_t stream) {
  const float* x   = (const float*)d_in[0];
  const float* y   = (const float*)d_in[1];
  const float* psi = (const float*)d_in[2];
  float* out = (float*)d_out;

  char* ws = (char*)d_ws;
  unsigned short* xb = (unsigned short*)ws;                                  // 8 MB
  unsigned short* yb = (unsigned short*)(ws + (size_t)N_ROWS * DIM * 2);     // 8 MB
  float* x2 = (float*)(ws + (size_t)(N_ROWS + M_ROWS) * DIM * 2);            // 64 KB
  float* rj = x2 + N_ROWS;                                                   // 64 KB (y2 - psi)
  unsigned int* rowmin = (unsigned int*)(rj + M_ROWS);                       // 64 KB
  double* partials = (double*)(rowmin + N_ROWS);                             // 1 KB

  prep_kernel<<<(N_ROWS + M_ROWS) / 4, 256, 0, stream>>>(x, y, psi, xb, yb, x2, rj, rowmin);
  gemm_min_kernel<<<(N_ROWS / 256) * 8, 256, 0, stream>>>(xb, yb, rj, rowmin);
  finish1_kernel<<<N_ROWS / 256, 256, 0, stream>>>(x2, rowmin, psi, partials);
  finish2_kernel<<<1, 64, 0, stream>>>(partials, out);
}

// Round 17
// 105.918 us; speedup vs baseline: 1.5735x; 1.1821x over previous
//
#include <hip/hip_runtime.h>
#include <hip/hip_bf16.h>
#include <hip/hip_fp8.h>

#define N_ROWS 16384
#define M_ROWS 16384
#define DIM 256
#define JT 32           // y-cols per j-iter
#define NJ 64           // j-iters per block (JT*NJ = 2048-col chunk)

typedef __attribute__((ext_vector_type(4))) float f32x4;

__device__ inline unsigned enc_f(float f) {
  unsigned u = __float_as_uint(f);
  return (u & 0x80000000u) ? ~u : (u | 0x80000000u);
}
__device__ inline float dec_f(unsigned u) {
  unsigned b = (u & 0x80000000u) ? (u & 0x7FFFFFFFu) : ~u;
  return __uint_as_float(b);
}

// Fused prep: blocks [0,4096) convert x -> xb8 (fp8 e4m3) + x2 + rowmin init;
// blocks [4096,8192) convert y -> yb8 + (y2 - psi). Row sums stay fp32-exact
// from the ORIGINAL floats; only the cross term is quantized.
__global__ __launch_bounds__(256) void prep_kernel(
    const float* __restrict__ x, const float* __restrict__ y,
    const float* __restrict__ psi,
    unsigned char* __restrict__ xb8, unsigned char* __restrict__ yb8,
    float* __restrict__ x2, float* __restrict__ rj,
    unsigned int* __restrict__ rowmin) {
  int bid  = blockIdx.x;
  int isY  = bid >= (N_ROWS / 4);
  int rb   = isY ? bid - N_ROWS / 4 : bid;
  int row  = rb * 4 + (threadIdx.x >> 6);
  int lane = threadIdx.x & 63;
  const float* in = isY ? y : x;
  unsigned char* outb = isY ? yb8 : xb8;
  const float4 v = *reinterpret_cast<const float4*>(in + (size_t)row * DIM + lane * 4);
  unsigned b0 = __hip_fp8_e4m3(v.x).__x;
  unsigned b1 = __hip_fp8_e4m3(v.y).__x;
  unsigned b2 = __hip_fp8_e4m3(v.z).__x;
  unsigned b3 = __hip_fp8_e4m3(v.w).__x;
  *reinterpret_cast<unsigned int*>(outb + (size_t)row * DIM + lane * 4) =
      b0 | (b1 << 8) | (b2 << 16) | (b3 << 24);
  float s = v.x * v.x + v.y * v.y + v.z * v.z + v.w * v.w;
#pragma unroll
  for (int m = 1; m < 64; m <<= 1) s += __shfl_xor(s, m, 64);
  if (lane == 0) {
    if (isY) rj[row] = s - psi[row];
    else { x2[row] = s; rowmin[row] = 0xFFFFFFFFu; }
  }
}

// R15 gemm skeleton, fp8 widths: register-resident-A (AGPR-pinned, 64 AGPR),
// M-streaming, fragment-major LDS (8KB tiles), 3-deep ring, counted vmcnt(2),
// 2-deep B-fragment ring (ds_read_b64) + sched_group_barrier {2 DS, 8 MFMA}.
// MFMA: f32_16x16x32_fp8_fp8 (same shape/lane geometry as bf16, half bytes).
__global__ __launch_bounds__(256, 2) void gemm_min_kernel(
    const unsigned char* __restrict__ xb8, const unsigned char* __restrict__ yb8,
    const float* __restrict__ rj, unsigned int* __restrict__ rowmin) {
  __shared__ unsigned char Bt[3][JT * DIM];  // 3 x 8 KiB

  const int bid    = blockIdx.x;       // 512 blocks, 2 per CU
  const int jchunk = bid & 7;          // == XCD id under round-robin dispatch
  const int strip  = bid >> 3;         // 0..63
  const int brow   = strip * 256;
  const int jbase0 = jchunk * (JT * NJ);

  const int tid = threadIdx.x;
  const int w = tid >> 6, lane = tid & 63;
  const int fr = lane & 15, g4 = lane >> 4;

  // ---- A fragments: rows brow + w*64 + m*16 + fr, k = ks*32 + g4*8; AGPR-pinned.
  long afr[4][8];
  {
    const unsigned char* aBase = xb8 + (size_t)(brow + w * 64 + fr) * DIM + g4 * 8;
#pragma unroll
    for (int m = 0; m < 4; ++m)
#pragma unroll
      for (int ks = 0; ks < 8; ++ks) {
        afr[m][ks] = *reinterpret_cast<const long*>(aBase + (size_t)(m * 16) * DIM + ks * 32);
        asm volatile("" : "+a"(afr[m][ks]));  // pin in AGPR file
      }
  }
  __builtin_amdgcn_sched_barrier(0);

  // ---- staging: wave w stages chunks w*4..w*4+3 (512B each) via 2 instrs
  // (each instr = 1KB = 2 adjacent chunks). chunk cc = n*8+ks holds the
  // (16-col group n, 32-k slice ks) fragment set as [fr][g4] 8B units.
  // LDS dest wave-uniform (lane-linear); per-lane global source.
  const int sfr = (lane & 31) >> 1;    // row within col-group
  const int sg  = (lane & 1) * 16;     // 16B half (two g4 slots)

#define STAGE(buf, j)                                                            \
  {                                                                              \
    _Pragma("unroll")                                                            \
    for (int c = 0; c < 2; ++c) {                                                \
      const int cc0 = w * 4 + c * 2;                                             \
      const int cc  = cc0 + (lane >> 5);                                         \
      const int sn = cc >> 3, sk = cc & 7;                                       \
      __builtin_amdgcn_global_load_lds(                                          \
          (const __attribute__((address_space(1))) void*)(                       \
              yb8 + (size_t)(jbase0 + (j) * JT + sn * 16 + sfr) * DIM + sk * 32 + sg), \
          (__attribute__((address_space(3))) void*)(&Bt[(buf)][cc0 * 512]), 16, 0, 0); \
    }                                                                            \
  }

  STAGE(0, 0);
  STAGE(1, 1);

  const float* rjc = rj + jbase0;
  float mn[4][4];
#pragma unroll
  for (int m = 0; m < 4; ++m)
#pragma unroll
    for (int r = 0; r < 4; ++r) mn[m][r] = 3.4e38f;

  int rb = 0;  // ring read index
#pragma unroll 1
  for (int j = 0; j < NJ; ++j) {
    if (j == NJ - 1) { asm volatile("s_waitcnt vmcnt(0)" ::: "memory"); }
    else             { asm volatile("s_waitcnt vmcnt(2)" ::: "memory"); }
    __builtin_amdgcn_sched_barrier(0);
    __builtin_amdgcn_s_barrier();
    __builtin_amdgcn_sched_barrier(0);

    // rv loads issued early; consumed only at iter end (latency hidden by MFMA).
    float rv0 = rjc[j * JT + fr];
    float rv1 = rjc[j * JT + 16 + fr];
    __builtin_amdgcn_sched_barrier(0);
    if (j + 2 < NJ) {
      int sb = rb + 2; if (sb >= 3) sb -= 3;
      STAGE(sb, j + 2);
    }
    __builtin_amdgcn_sched_barrier(0);

    f32x4 acc[4][2];
#pragma unroll
    for (int m = 0; m < 4; ++m)
#pragma unroll
      for (int n = 0; n < 2; ++n) acc[m][n] = (f32x4){0.f, 0.f, 0.f, 0.f};

    const unsigned char* B = &Bt[rb][0];
    // Fragment byte address: chunk (n*8+ks)*512 + fr*32 + g4*8.
#define BADDR(n, ks) (((n) * 8 + (ks)) * 512 + fr * 32 + g4 * 8)
    // 2-deep B-fragment prefetch ring (indices compile-time after full unroll).
    long pb0[3], pb1[3];
    pb0[0] = *reinterpret_cast<const long*>(&B[BADDR(0, 0)]);
    pb1[0] = *reinterpret_cast<const long*>(&B[BADDR(1, 0)]);
    pb0[1] = *reinterpret_cast<const long*>(&B[BADDR(0, 1)]);
    pb1[1] = *reinterpret_cast<const long*>(&B[BADDR(1, 1)]);

    __builtin_amdgcn_s_setprio(1);
    __builtin_amdgcn_sched_barrier(0);
#pragma unroll
    for (int ks = 0; ks < 8; ++ks) {
      const int cs = ks % 3;
      const int ns = (ks + 2) % 3;
      if (ks < 6) {
        pb0[ns] = *reinterpret_cast<const long*>(&B[BADDR(0, ks + 2)]);
        pb1[ns] = *reinterpret_cast<const long*>(&B[BADDR(1, ks + 2)]);
      }
#pragma unroll
      for (int m = 0; m < 4; ++m) {
        acc[m][0] = __builtin_amdgcn_mfma_f32_16x16x32_fp8_fp8(afr[m][ks], pb0[cs], acc[m][0], 0, 0, 0);
        acc[m][1] = __builtin_amdgcn_mfma_f32_16x16x32_fp8_fp8(afr[m][ks], pb1[cs], acc[m][1], 0, 0, 0);
      }
      // Pin emission: 2 ds_reads ride under each 8-MFMA cluster.
      if (ks < 6) {
        __builtin_amdgcn_sched_group_barrier(0x100, 2, 0);  // 2 DS_READ
        __builtin_amdgcn_sched_group_barrier(0x008, 8, 0);  // 8 MFMA
      } else {
        __builtin_amdgcn_sched_group_barrier(0x008, 8, 0);  // 8 MFMA
      }
    }
    __builtin_amdgcn_sched_barrier(0);
#undef BADDR
    __builtin_amdgcn_s_setprio(0);

    // fold: val = rv - 2*dot ; running min
#pragma unroll
    for (int m = 0; m < 4; ++m)
#pragma unroll
      for (int r = 0; r < 4; ++r) {
        mn[m][r] = fminf(mn[m][r], fmaf(-2.f, acc[m][0][r], rv0));
        mn[m][r] = fminf(mn[m][r], fmaf(-2.f, acc[m][1][r], rv1));
      }
    rb = rb + 1; if (rb >= 3) rb -= 3;
  }
#undef STAGE

  // Row-min over chunk: reduce min over the 16 fr-lanes, then one atomic per row.
#pragma unroll
  for (int m = 0; m < 4; ++m)
#pragma unroll
    for (int r = 0; r < 4; ++r) {
      float v = mn[m][r];
#pragma unroll
      for (int s = 1; s < 16; s <<= 1) v = fminf(v, __shfl_xor(v, s, 64));
      if (fr == 0) {
        int row = brow + w * 64 + m * 16 + g4 * 4 + r;
        atomicMin(&rowmin[row], enc_f(v));
      }
    }
}

// Stage 1: 64 blocks; block b sums rows [b*256, (b+1)*256) of x2+rowmin (and
// psi) into partials — fixed reduction order, deterministic.
__global__ __launch_bounds__(256) void finish1_kernel(
    const float* __restrict__ x2, const unsigned int* __restrict__ rowmin,
    const float* __restrict__ psi, double* __restrict__ partials) {
  int tid = threadIdx.x;
  int i = blockIdx.x * 256 + tid;
  double s0 = (double)x2[i] + (double)dec_f(rowmin[i]);
  double s1 = (double)psi[i];
  __shared__ double sm0[4], sm1[4];
#pragma unroll
  for (int m = 1; m < 64; m <<= 1) { s0 += __shfl_xor(s0, m, 64); s1 += __shfl_xor(s1, m, 64); }
  if ((tid & 63) == 0) { sm0[tid >> 6] = s0; sm1[tid >> 6] = s1; }
  __syncthreads();
  if (tid == 0) {
    partials[blockIdx.x]      = sm0[0] + sm0[1] + sm0[2] + sm0[3];
    partials[64 + blockIdx.x] = sm1[0] + sm1[1] + sm1[2] + sm1[3];
  }
}

// Stage 2: one wave reduces the 64 partials.
__global__ __launch_bounds__(64) void finish2_kernel(
    const double* __restrict__ partials, float* __restrict__ out) {
  int lane = threadIdx.x;
  double s0 = partials[lane];
  double s1 = partials[64 + lane];
#pragma unroll
  for (int m = 1; m < 64; m <<= 1) { s0 += __shfl_xor(s0, m, 64); s1 += __shfl_xor(s1, m, 64); }
  if (lane == 0) {
    out[0] = (float)(s0 / (double)N_ROWS);
    out[1] = (float)(s1 / (double)M_ROWS);
  }
}

extern "C" void kernel_launch(void* const* d_in, const int* in_sizes, int n_in,
                              void* d_out, int out_size, void* d_ws, size_t ws_size,
                              hipStream_t stream) {
  const float* x   = (const float*)d_in[0];
  const float* y   = (const float*)d_in[1];
  const float* psi = (const float*)d_in[2];
  float* out = (float*)d_out;

  char* ws = (char*)d_ws;
  unsigned char* xb8 = (unsigned char*)ws;                                   // 4 MB
  unsigned char* yb8 = (unsigned char*)(ws + (size_t)N_ROWS * DIM);          // 4 MB
  float* x2 = (float*)(ws + (size_t)(N_ROWS + M_ROWS) * DIM);                // 64 KB
  float* rj = x2 + N_ROWS;                                                   // 64 KB (y2 - psi)
  unsigned int* rowmin = (unsigned int*)(rj + M_ROWS);                       // 64 KB
  double* partials = (double*)(rowmin + N_ROWS);                             // 1 KB

  prep_kernel<<<(N_ROWS + M_ROWS) / 4, 256, 0, stream>>>(x, y, psi, xb8, yb8, x2, rj, rowmin);
  gemm_min_kernel<<<(N_ROWS / 256) * 8, 256, 0, stream>>>(xb8, yb8, rj, rowmin);
  finish1_kernel<<<N_ROWS / 256, 256, 0, stream>>>(x2, rowmin, psi, partials);
  finish2_kernel<<<1, 64, 0, stream>>>(partials, out);
}

// Round 18
// 79.635 us; speedup vs baseline: 2.0928x; 1.3300x over previous
//
#include <hip/hip_runtime.h>
#include <hip/hip_bf16.h>
#include <hip/hip_fp8.h>

#define N_ROWS 16384
#define M_ROWS 16384
#define DIM 256
#define JT 32           // y-cols per j-iter
#define NJ 64           // j-iters per block (JT*NJ = 2048-col chunk)

typedef __attribute__((ext_vector_type(4))) float f32x4;
typedef __attribute__((ext_vector_type(4))) int   i32x4;
typedef __attribute__((ext_vector_type(8))) int   i32x8;

__device__ inline unsigned enc_f(float f) {
  unsigned u = __float_as_uint(f);
  return (u & 0x80000000u) ? ~u : (u | 0x80000000u);
}
__device__ inline float dec_f(unsigned u) {
  unsigned b = (u & 0x80000000u) ? (u & 0x7FFFFFFFu) : ~u;
  return __uint_as_float(b);
}

// Fused prep: blocks [0,4096) convert x -> xb8 (fp8 e4m3) + x2 + rowmin init;
// blocks [4096,8192) convert y -> yb8 + (y2 - psi). Row sums stay fp32-exact
// from the ORIGINAL floats; only the cross term is quantized.
__global__ __launch_bounds__(256) void prep_kernel(
    const float* __restrict__ x, const float* __restrict__ y,
    const float* __restrict__ psi,
    unsigned char* __restrict__ xb8, unsigned char* __restrict__ yb8,
    float* __restrict__ x2, float* __restrict__ rj,
    unsigned int* __restrict__ rowmin) {
  int bid  = blockIdx.x;
  int isY  = bid >= (N_ROWS / 4);
  int rb   = isY ? bid - N_ROWS / 4 : bid;
  int row  = rb * 4 + (threadIdx.x >> 6);
  int lane = threadIdx.x & 63;
  const float* in = isY ? y : x;
  unsigned char* outb = isY ? yb8 : xb8;
  const float4 v = *reinterpret_cast<const float4*>(in + (size_t)row * DIM + lane * 4);
  unsigned b0 = __hip_fp8_e4m3(v.x).__x;
  unsigned b1 = __hip_fp8_e4m3(v.y).__x;
  unsigned b2 = __hip_fp8_e4m3(v.z).__x;
  unsigned b3 = __hip_fp8_e4m3(v.w).__x;
  *reinterpret_cast<unsigned int*>(outb + (size_t)row * DIM + lane * 4) =
      b0 | (b1 << 8) | (b2 << 16) | (b3 << 24);
  float s = v.x * v.x + v.y * v.y + v.z * v.z + v.w * v.w;
#pragma unroll
  for (int m = 1; m < 64; m <<= 1) s += __shfl_xor(s, m, 64);
  if (lane == 0) {
    if (isY) rj[row] = s - psi[row];
    else { x2[row] = s; rowmin[row] = 0xFFFFFFFFu; }
  }
}

// R17 skeleton, MX-scaled fp8 K=128 MFMA (2x rate), unit scales (0x7F = 1.0
// in E8M0 -> math identical to plain fp8). 16 MFMAs/wave-iter.
// LDS: 4 chunks x 2KB per tile; chunk cc = n*2 + ksub holds the (16-col group
// n, 128-k slice ksub) fragment set, split as two 1KB lane-linear pieces
// (piece h = bytes h*16..h*16+15 of each lane's 32) -> conflict-free b128.
__global__ __launch_bounds__(256, 2) void gemm_min_kernel(
    const unsigned char* __restrict__ xb8, const unsigned char* __restrict__ yb8,
    const float* __restrict__ rj, unsigned int* __restrict__ rowmin) {
  __shared__ unsigned char Bt[3][JT * DIM];  // 3 x 8 KiB

  const int bid    = blockIdx.x;       // 512 blocks, 2 per CU
  const int jchunk = bid & 7;          // == XCD id under round-robin dispatch
  const int strip  = bid >> 3;         // 0..63
  const int brow   = strip * 256;
  const int jbase0 = jchunk * (JT * NJ);

  const int tid = threadIdx.x;
  const int w = tid >> 6, lane = tid & 63;
  const int fr = lane & 15, g4 = lane >> 4;

  const int SC1 = 0x7F7F7F7F;  // E8M0 unit scales for all block-select bytes

  // ---- A fragments (16x16x128): row = brow + w*64 + m*16 + fr,
  // k = kq*128 + g4*32 .. +32 (32 contiguous bytes/lane); AGPR-pinned.
  i32x8 afr[4][2];
  {
    const unsigned char* aBase = xb8 + (size_t)(brow + w * 64 + fr) * DIM + g4 * 32;
#pragma unroll
    for (int m = 0; m < 4; ++m)
#pragma unroll
      for (int kq = 0; kq < 2; ++kq) {
        afr[m][kq] = *reinterpret_cast<const i32x8*>(aBase + (size_t)(m * 16) * DIM + kq * 128);
        asm volatile("" : "+a"(afr[m][kq]));  // pin in AGPR file
      }
  }
  __builtin_amdgcn_sched_barrier(0);

  // ---- staging: 8 pieces x 1KB per tile; wave w stages pieces w*2, w*2+1.
  // piece p: chunk cc = p>>1 (n = cc>>1, ksub = cc&1), half h = p&1.
  // LDS dest lane-linear; per-lane global source row n*16+(lane&15),
  // k = ksub*128 + (lane>>4)*32 + h*16.
  const int sr16 = lane & 15;
  const int sk32 = (lane >> 4) * 32;

#define STAGE(buf, j)                                                            \
  {                                                                              \
    _Pragma("unroll")                                                            \
    for (int c = 0; c < 2; ++c) {                                                \
      const int p = w * 2 + c;                                                   \
      const int cc = p >> 1, h = p & 1;                                          \
      __builtin_amdgcn_global_load_lds(                                          \
          (const __attribute__((address_space(1))) void*)(                       \
              yb8 + (size_t)(jbase0 + (j) * JT + (cc >> 1) * 16 + sr16) * DIM +  \
              (cc & 1) * 128 + sk32 + h * 16),                                   \
          (__attribute__((address_space(3))) void*)(&Bt[(buf)][cc * 2048 + h * 1024]), \
          16, 0, 0);                                                             \
    }                                                                            \
  }

  // LOADF: B fragment for group g (kq = g>>1, ng = g&1; chunk cc = ng*2+kq):
  // two lane-linear b128 reads (conflict-free).
#define LOADF(dst, g)                                                            \
  {                                                                              \
    const int cc = ((g) & 1) * 2 + ((g) >> 1);                                   \
    i32x4 lo = *reinterpret_cast<const i32x4*>(&B[cc * 2048 + lane * 16]);       \
    i32x4 hi = *reinterpret_cast<const i32x4*>(&B[cc * 2048 + 1024 + lane * 16]); \
    dst[0] = lo[0]; dst[1] = lo[1]; dst[2] = lo[2]; dst[3] = lo[3];              \
    dst[4] = hi[0]; dst[5] = hi[1]; dst[6] = hi[2]; dst[7] = hi[3];              \
  }

#define MFMA4(KQ, NG, PB)                                                        \
  {                                                                              \
    _Pragma("unroll")                                                            \
    for (int m = 0; m < 4; ++m)                                                  \
      acc[m][(NG)] = __builtin_amdgcn_mfma_scale_f32_16x16x128_f8f6f4(           \
          afr[m][(KQ)], PB, acc[m][(NG)], 0, 0, 0, SC1, 0, SC1);                 \
  }

  STAGE(0, 0);
  STAGE(1, 1);

  const float* rjc = rj + jbase0;
  float mn[4][4];
#pragma unroll
  for (int m = 0; m < 4; ++m)
#pragma unroll
    for (int r = 0; r < 4; ++r) mn[m][r] = 3.4e38f;

  int rb = 0;  // ring read index
#pragma unroll 1
  for (int j = 0; j < NJ; ++j) {
    if (j == NJ - 1) { asm volatile("s_waitcnt vmcnt(0)" ::: "memory"); }
    else             { asm volatile("s_waitcnt vmcnt(2)" ::: "memory"); }
    __builtin_amdgcn_sched_barrier(0);
    __builtin_amdgcn_s_barrier();
    __builtin_amdgcn_sched_barrier(0);

    // rv loads issued early; consumed only at iter end (latency hidden by MFMA).
    float rv0 = rjc[j * JT + fr];
    float rv1 = rjc[j * JT + 16 + fr];
    __builtin_amdgcn_sched_barrier(0);
    if (j + 2 < NJ) {
      int sb = rb + 2; if (sb >= 3) sb -= 3;
      STAGE(sb, j + 2);
    }
    __builtin_amdgcn_sched_barrier(0);

    f32x4 acc[4][2];
#pragma unroll
    for (int m = 0; m < 4; ++m)
#pragma unroll
      for (int n = 0; n < 2; ++n) acc[m][n] = (f32x4){0.f, 0.f, 0.f, 0.f};

    const unsigned char* B = &Bt[rb][0];
    i32x8 pbA, pbB;
    LOADF(pbA, 0);

    __builtin_amdgcn_s_setprio(1);
    __builtin_amdgcn_sched_barrier(0);
    // g=0: (kq0, ng0)
    LOADF(pbB, 1);
    MFMA4(0, 0, pbA);
    __builtin_amdgcn_sched_group_barrier(0x100, 2, 0);
    __builtin_amdgcn_sched_group_barrier(0x008, 4, 0);
    // g=1: (kq0, ng1)
    LOADF(pbA, 2);
    MFMA4(0, 1, pbB);
    __builtin_amdgcn_sched_group_barrier(0x100, 2, 0);
    __builtin_amdgcn_sched_group_barrier(0x008, 4, 0);
    // g=2: (kq1, ng0)
    LOADF(pbB, 3);
    MFMA4(1, 0, pbA);
    __builtin_amdgcn_sched_group_barrier(0x100, 2, 0);
    __builtin_amdgcn_sched_group_barrier(0x008, 4, 0);
    // g=3: (kq1, ng1)
    MFMA4(1, 1, pbB);
    __builtin_amdgcn_sched_group_barrier(0x008, 4, 0);
    __builtin_amdgcn_sched_barrier(0);
    __builtin_amdgcn_s_setprio(0);

    // fold: val = rv - 2*dot ; running min
#pragma unroll
    for (int m = 0; m < 4; ++m)
#pragma unroll
      for (int r = 0; r < 4; ++r) {
        mn[m][r] = fminf(mn[m][r], fmaf(-2.f, acc[m][0][r], rv0));
        mn[m][r] = fminf(mn[m][r], fmaf(-2.f, acc[m][1][r], rv1));
      }
    rb = rb + 1; if (rb >= 3) rb -= 3;
  }
#undef MFMA4
#undef LOADF
#undef STAGE

  // Row-min over chunk: reduce min over the 16 fr-lanes, then one atomic per row.
#pragma unroll
  for (int m = 0; m < 4; ++m)
#pragma unroll
    for (int r = 0; r < 4; ++r) {
      float v = mn[m][r];
#pragma unroll
      for (int s = 1; s < 16; s <<= 1) v = fminf(v, __shfl_xor(v, s, 64));
      if (fr == 0) {
        int row = brow + w * 64 + m * 16 + g4 * 4 + r;
        atomicMin(&rowmin[row], enc_f(v));
      }
    }
}

// Stage 1: 64 blocks; block b sums rows [b*256, (b+1)*256) of x2+rowmin (and
// psi) into partials — fixed reduction order, deterministic.
__global__ __launch_bounds__(256) void finish1_kernel(
    const float* __restrict__ x2, const unsigned int* __restrict__ rowmin,
    const float* __restrict__ psi, double* __restrict__ partials) {
  int tid = threadIdx.x;
  int i = blockIdx.x * 256 + tid;
  double s0 = (double)x2[i] + (double)dec_f(rowmin[i]);
  double s1 = (double)psi[i];
  __shared__ double sm0[4], sm1[4];
#pragma unroll
  for (int m = 1; m < 64; m <<= 1) { s0 += __shfl_xor(s0, m, 64); s1 += __shfl_xor(s1, m, 64); }
  if ((tid & 63) == 0) { sm0[tid >> 6] = s0; sm1[tid >> 6] = s1; }
  __syncthreads();
  if (tid == 0) {
    partials[blockIdx.x]      = sm0[0] + sm0[1] + sm0[2] + sm0[3];
    partials[64 + blockIdx.x] = sm1[0] + sm1[1] + sm1[2] + sm1[3];
  }
}

// Stage 2: one wave reduces the 64 partials.
__global__ __launch_bounds__(64) void finish2_kernel(
    const double* __restrict__ partials, float* __restrict__ out) {
  int lane = threadIdx.x;
  double s0 = partials[lane];
  double s1 = partials[64 + lane];
#pragma unroll
  for (int m = 1; m < 64; m <<= 1) { s0 += __shfl_xor(s0, m, 64); s1 += __shfl_xor(s1, m, 64); }
  if (lane == 0) {
    out[0] = (float)(s0 / (double)N_ROWS);
    out[1] = (float)(s1 / (double)M_ROWS);
  }
}

extern "C" void kernel_launch(void* const* d_in, const int* in_sizes, int n_in,
                              void* d_out, int out_size, void* d_ws, size_t ws_size,
                              hipStream_t stream) {
  const float* x   = (const float*)d_in[0];
  const float* y   = (const float*)d_in[1];
  const float* psi = (const float*)d_in[2];
  float* out = (float*)d_out;

  char* ws = (char*)d_ws;
  unsigned char* xb8 = (unsigned char*)ws;                                   // 4 MB
  unsigned char* yb8 = (unsigned char*)(ws + (size_t)N_ROWS * DIM);          // 4 MB
  float* x2 = (float*)(ws + (size_t)(N_ROWS + M_ROWS) * DIM);                // 64 KB
  float* rj = x2 + N_ROWS;                                                   // 64 KB (y2 - psi)
  unsigned int* rowmin = (unsigned int*)(rj + M_ROWS);                       // 64 KB
  double* partials = (double*)(rowmin + N_ROWS);                             // 1 KB

  prep_kernel<<<(N_ROWS + M_ROWS) / 4, 256, 0, stream>>>(x, y, psi, xb8, yb8, x2, rj, rowmin);
  gemm_min_kernel<<<(N_ROWS / 256) * 8, 256, 0, stream>>>(xb8, yb8, rj, rowmin);
  finish1_kernel<<<N_ROWS / 256, 256, 0, stream>>>(x2, rowmin, psi, partials);
  finish2_kernel<<<1, 64, 0, stream>>>(partials, out);
}